// Round 4
// baseline (826.725 us; speedup 1.0000x reference)
//
#include <hip/hip_runtime.h>
#include <hip/hip_bf16.h>
#include <math.h>

#define B   256
#define IU  8
#define IC  1152
#define NU  10
#define US  16

#define SNC 72     // c-chunks in s-pass
#define SCC 16     // channels per chunk
#define WROW 140   // padded LDS row per (cc,d): slot(uq)=uq*8+(uq>>2)*4 -> 2-way max (free)

// ---------------- s pass v3 ----------------
// s[b,d,u] = sum_{c,i} cT[d,c] * W[c,d,u,i] * x[b,i,c]
// grid 576 = 72 c-chunks x 8 b-tiles(32b, NB=2/thread). W staged per-4cc in LDS,
// double-buffered via register prefetch; x transposed to [bl][cc][i] once.
__global__ __launch_bounds__(256, 2) void s_pass(const float* __restrict__ x,
                                                 const float* __restrict__ W,
                                                 const float* __restrict__ cT,
                                                 float* __restrict__ sp,
                                                 float scale) {
    __shared__ float xs[32 * SCC * IU];       // [bl][cc][i]  16 KB
    __shared__ float wbuf[2][4 * NU * WROW];  // 44.8 KB
    __shared__ float cl[NU * SCC];
    const int tid = threadIdx.x;
    const int ch = blockIdx.x % SNC;
    const int bt = blockIdx.x / SNC;
    const int b0 = bt * 32, c0 = ch * SCC;

    // x stage: 1024 f4, transpose to [bl][cc][i]
#pragma unroll
    for (int k = 0; k < 4; k++) {
        int j = tid + k * 256;
        int c4 = j & 3, i = (j >> 2) & 7, bl = j >> 5;
        float4 t = *(const float4*)(x + (size_t)(b0 + bl) * (IU * IC) + i * IC + c0 + c4 * 4);
        xs[(bl * SCC + c4 * 4 + 0) * IU + i] = t.x;
        xs[(bl * SCC + c4 * 4 + 1) * IU + i] = t.y;
        xs[(bl * SCC + c4 * 4 + 2) * IU + i] = t.z;
        xs[(bl * SCC + c4 * 4 + 3) * IU + i] = t.w;
    }
    if (tid < NU * SCC) {
        int d = tid / SCC, cc = tid % SCC;
        cl[tid] = cT ? cT[d * IC + c0 + cc] : 1.0f;
    }
    // W chunk 0 -> buf0 (chunk = 4 channels = 1280 f4, 5 f4/thread)
    float4 pf[5];
    const float* wsrc = W + (size_t)c0 * 1280;
#pragma unroll
    for (int k = 0; k < 5; k++)
        pf[k] = *(const float4*)(wsrc + (size_t)(tid + k * 256) * 4);
#pragma unroll
    for (int k = 0; k < 5; k++) {
        int j = tid + k * 256;
        int cc4 = j / 320, r = j % 320, dd = r >> 5, q = r & 31, u2 = q >> 1, h = q & 1;
        *(float4*)&wbuf[0][(cc4 * NU + dd) * WROW + u2 * 8 + (u2 >> 2) * 4 + h * 4] = pf[k];
    }
    __syncthreads();

    const int uq = tid & 15;
    const int bg = tid >> 4;
    const int uqs = uq * 8 + (uq >> 2) * 4;
    float acc[NU][2];
#pragma unroll
    for (int d = 0; d < NU; d++) acc[d][0] = acc[d][1] = 0.0f;

    for (int cch = 0; cch < 4; cch++) {
        const int cur = cch & 1;
        if (cch < 3) {
            const float* w2 = wsrc + (size_t)(cch + 1) * 5120;
#pragma unroll
            for (int k = 0; k < 5; k++)
                pf[k] = *(const float4*)(w2 + (size_t)(tid + k * 256) * 4);
        }
#pragma unroll
        for (int c4 = 0; c4 < 4; c4++) {
            const int cc = cch * 4 + c4;
            float xv0[8], xv1[8];
            *(float4*)&xv0[0] = *(const float4*)&xs[((bg * 2 + 0) * SCC + cc) * IU + 0];
            *(float4*)&xv0[4] = *(const float4*)&xs[((bg * 2 + 0) * SCC + cc) * IU + 4];
            *(float4*)&xv1[0] = *(const float4*)&xs[((bg * 2 + 1) * SCC + cc) * IU + 0];
            *(float4*)&xv1[4] = *(const float4*)&xs[((bg * 2 + 1) * SCC + cc) * IU + 4];
#pragma unroll
            for (int d = 0; d < NU; d++) {
                const float* wr = &wbuf[cur][(c4 * NU + d) * WROW + uqs];
                float4 w0 = *(const float4*)(wr);
                float4 w1 = *(const float4*)(wr + 4);
                float cw = cl[d * SCC + cc];
                float d0 = w0.x*xv0[0] + w0.y*xv0[1] + w0.z*xv0[2] + w0.w*xv0[3]
                         + w1.x*xv0[4] + w1.y*xv0[5] + w1.z*xv0[6] + w1.w*xv0[7];
                float d1 = w0.x*xv1[0] + w0.y*xv1[1] + w0.z*xv1[2] + w0.w*xv1[3]
                         + w1.x*xv1[4] + w1.y*xv1[5] + w1.z*xv1[6] + w1.w*xv1[7];
                acc[d][0] += cw * d0;
                acc[d][1] += cw * d1;
            }
        }
        if (cch < 3) {
            // write prefetched chunk into the other buffer (no race: peers only read wbuf[cur])
#pragma unroll
            for (int k = 0; k < 5; k++) {
                int j = tid + k * 256;
                int cc4 = j / 320, r = j % 320, dd = r >> 5, q = r & 31, u2 = q >> 1, h = q & 1;
                *(float4*)&wbuf[1 - cur][(cc4 * NU + dd) * WROW + u2 * 8 + (u2 >> 2) * 4 + h * 4] = pf[k];
            }
            __syncthreads();
        }
    }
#pragma unroll
    for (int bb = 0; bb < 2; bb++) {
        const int b = b0 + bg * 2 + bb;
#pragma unroll
        for (int d = 0; d < NU; d++)
            sp[(((size_t)ch * B + b) * NU + d) * US + uq] = acc[d][bb] * scale;
    }
}

// ---------------- squash ----------------
__global__ __launch_bounds__(192) void squash_k(const float* __restrict__ sp,
                                                float* __restrict__ vout, int nc) {
    __shared__ float smag[NU * US];
    const int b = blockIdx.x;
    const int tid = threadIdx.x;
    const int d = tid >> 4, uq = tid & 15;
    float s = 0.0f;
    if (d < NU) {
        for (int chp = 0; chp < nc; chp++)
            s += sp[(((size_t)chp * B + b) * NU + d) * US + uq];
        smag[d * US + uq] = s * s;
    }
    __syncthreads();
    if (d < NU) {
        float msq = 0.0f;
#pragma unroll
        for (int dd = 0; dd < NU; dd++) msq += smag[dd * US + uq];
        float f = msq / ((1.0f + msq) * sqrtf(msq));
        vout[((size_t)b * NU + d) * US + uq] = s * f;
    }
}

// ---------------- agree pass v3 ----------------
// agree[c,d] = sum_{b,u} (sum_i W[c,d,u,i]*x[b,i,c]) * v[b,d,u]
// grid 720 = 36 ct(32c) x 10 d x 2 bh(128b). W+v staged in LDS once (low VGPR);
// x in 4 rounds of 32 b, register-prefetched during compute.
__global__ __launch_bounds__(256, 2) void agree_k(const float* __restrict__ x,
                                                  const float* __restrict__ W,
                                                  const float* __restrict__ v,
                                                  float* __restrict__ ap) {
    __shared__ float wst[32 * 132];      // [c][u*8+i] pad->4-way max
    __shared__ float vl[128 * 16];       // [bl][u]
    __shared__ float xs[32 * IU * 32];   // [bl][i][c] 32 KB per round
    __shared__ float red[8 * 33];
    const int tid = threadIdx.x;
    const int ct = blockIdx.x % 36;
    const int r0 = blockIdx.x / 36;
    const int d = r0 % NU;
    const int bh = r0 / NU;
    const int c0 = ct * 32, b0 = bh * 128;

#pragma unroll
    for (int k = 0; k < 4; k++) {
        int j = tid + k * 256;
        int c = j >> 5, q = j & 31;
        *(float4*)&wst[c * 132 + q * 4] =
            *(const float4*)(W + (size_t)(c0 + c) * 1280 + d * 128 + q * 4);
    }
#pragma unroll
    for (int k = 0; k < 2; k++) {
        int j = tid + k * 256;
        int bl = j >> 2, u4 = j & 3;
        *(float4*)&vl[bl * 16 + u4 * 4] =
            *(const float4*)(v + ((size_t)(b0 + bl) * NU + d) * US + u4 * 4);
    }
    float4 px[8];
#pragma unroll
    for (int k = 0; k < 8; k++) {
        int j = tid + k * 256;
        int c4 = j & 7, i = (j >> 3) & 7, bl = j >> 6;
        px[k] = *(const float4*)(x + (size_t)(b0 + bl) * (IU * IC) + i * IC + c0 + c4 * 4);
    }

    const int cl_ = tid & 31;
    const int bq = tid >> 5;
    float acc = 0.0f;

    for (int rr = 0; rr < 4; rr++) {
        __syncthreads();    // xs free (prev round consumed); also covers wst/vl at rr=0
#pragma unroll
        for (int k = 0; k < 8; k++) {
            int j = tid + k * 256;
            int c4 = j & 7, i = (j >> 3) & 7, bl = j >> 6;
            *(float4*)&xs[(bl * IU + i) * 32 + c4 * 4] = px[k];
        }
        __syncthreads();
        if (rr < 3) {
#pragma unroll
            for (int k = 0; k < 8; k++) {
                int j = tid + k * 256;
                int c4 = j & 7, i = (j >> 3) & 7, bl = j >> 6;
                px[k] = *(const float4*)(x + (size_t)(b0 + (rr + 1) * 32 + bl) * (IU * IC) + i * IC + c0 + c4 * 4);
            }
        }
        float xv[4][8];
#pragma unroll
        for (int bb = 0; bb < 4; bb++) {
            const int bl = bq * 4 + bb;
#pragma unroll
            for (int i = 0; i < 8; i++) xv[bb][i] = xs[(bl * IU + i) * 32 + cl_];
        }
#pragma unroll
        for (int u = 0; u < US; u++) {
            const float* wr = &wst[cl_ * 132 + u * 8];
            float4 w0 = *(const float4*)(wr);
            float4 w1 = *(const float4*)(wr + 4);
#pragma unroll
            for (int bb = 0; bb < 4; bb++) {
                float vv = vl[(rr * 32 + bq * 4 + bb) * 16 + u];
                float uh = w0.x*xv[bb][0] + w0.y*xv[bb][1] + w0.z*xv[bb][2] + w0.w*xv[bb][3]
                         + w1.x*xv[bb][4] + w1.y*xv[bb][5] + w1.z*xv[bb][6] + w1.w*xv[bb][7];
                acc += uh * vv;
            }
        }
    }
    red[bq * 33 + cl_] = acc;
    __syncthreads();
    if (tid < 32) {
        float s = 0.0f;
#pragma unroll
        for (int g = 0; g < 8; g++) s += red[g * 33 + tid];
        ap[((size_t)bh * NU + d) * IC + c0 + tid] = s;
    }
}

// ---------------- b update + softmax over channels ----------------
__global__ __launch_bounds__(384) void bsm_k(const float* __restrict__ ap,
                                             float* __restrict__ bij,
                                             float* __restrict__ cT,
                                             int first) {
    __shared__ float wred[8];
    __shared__ float bcast;
    const int d = blockIdx.x;
    const int tid = threadIdx.x;
    float bn[3];
    float lmax = -1e30f;
#pragma unroll
    for (int k = 0; k < 3; k++) {
        int c = tid + k * 384;
        float a = ap[(0 * NU + d) * IC + c] + ap[((size_t)1 * NU + d) * IC + c];
        a *= (1.0f / (float)B);
        float bo = first ? 0.0f : bij[d * IC + c];
        bn[k] = bo + a;
        bij[d * IC + c] = bn[k];
        lmax = fmaxf(lmax, bn[k]);
    }
    for (int off = 32; off > 0; off >>= 1) lmax = fmaxf(lmax, __shfl_down(lmax, off, 64));
    const int wid = tid >> 6, lane = tid & 63;
    if (lane == 0) wred[wid] = lmax;
    __syncthreads();
    if (tid == 0) {
        float m = wred[0];
        for (int w_ = 1; w_ < 6; w_++) m = fmaxf(m, wred[w_]);
        bcast = m;
    }
    __syncthreads();
    const float mx = bcast;
    float e[3];
    float lsum = 0.0f;
#pragma unroll
    for (int k = 0; k < 3; k++) { e[k] = expf(bn[k] - mx); lsum += e[k]; }
    for (int off = 32; off > 0; off >>= 1) lsum += __shfl_down(lsum, off, 64);
    if (lane == 0) wred[wid] = lsum;
    __syncthreads();
    if (tid == 0) {
        float s2 = 0.0f;
        for (int w_ = 0; w_ < 6; w_++) s2 += wred[w_];
        bcast = 1.0f / s2;
    }
    __syncthreads();
    const float inv = bcast;
#pragma unroll
    for (int k = 0; k < 3; k++) cT[d * IC + tid + k * 384] = e[k] * inv;
}

extern "C" void kernel_launch(void* const* d_in, const int* in_sizes, int n_in,
                              void* d_out, int out_size, void* d_ws, size_t ws_size,
                              hipStream_t stream) {
    const float* x = (const float*)d_in[0];   // [256, 8, 1152]
    const float* W = (const float*)d_in[1];   // [1, 1152, 10, 16, 8]
    float* out = (float*)d_out;               // [256, 10, 16] fp32

    // workspace (floats), ~12.1 MB total (R3 ran the 15.7 MB config -> fits)
    float* sp  = (float*)d_ws;                       // 72*256*160 = 2,949,120
    float* v   = sp + (size_t)SNC * B * NU * US;     // 40,960
    float* bij = v + (size_t)B * NU * US;            // 11,520  [d][c]
    float* cT  = bij + (size_t)NU * IC;              // 11,520  [d][c]
    float* apg = cT + (size_t)NU * IC;               // 2*10*1152 = 23,040

    const float inv_ic = 1.0f / (float)IC;

    // iteration 1 (c uniform = 1/1152)
    s_pass<<<576, 256, 0, stream>>>(x, W, nullptr, sp, inv_ic);
    squash_k<<<B, 192, 0, stream>>>(sp, v, SNC);
    agree_k<<<720, 256, 0, stream>>>(x, W, v, apg);
    bsm_k<<<NU, 384, 0, stream>>>(apg, bij, cT, 1);
    // iteration 2
    s_pass<<<576, 256, 0, stream>>>(x, W, cT, sp, 1.0f);
    squash_k<<<B, 192, 0, stream>>>(sp, v, SNC);
    agree_k<<<720, 256, 0, stream>>>(x, W, v, apg);
    bsm_k<<<NU, 384, 0, stream>>>(apg, bij, cT, 0);
    // iteration 3 (agree not needed after final squash)
    s_pass<<<576, 256, 0, stream>>>(x, W, cT, sp, 1.0f);
    squash_k<<<B, 192, 0, stream>>>(sp, out, SNC);
}

// Round 5
// 324.292 us; speedup vs baseline: 2.5493x; 2.5493x over previous
//
#include <hip/hip_runtime.h>
#include <hip/hip_bf16.h>
#include <math.h>

#define B   256
#define IU  8
#define IC  1152
#define NU  10
#define US  16

#define SNC 72     // c-chunks (16 ch each) for s-pass partials

typedef unsigned int u32;
// async global->LDS, 16B per lane. g: per-lane global src (incl +lane*4 floats),
// l: wave-uniform LDS base; HW writes lane i at l + i*16B.
__device__ __forceinline__ void gl_lds16(const float* g, float* l) {
    __builtin_amdgcn_global_load_lds((const __attribute__((address_space(1))) u32*)g,
                                     (__attribute__((address_space(3))) u32*)l, 16, 0, 0);
}

// ---------------- s pass v4 ----------------
// s[b,d,u] = sum_{c,i} cT[d,c] * W[c,d,u,i] * x[b,i,c]
// grid 576 = 72 c-chunks(16c) x 8 b-tiles(32b, 2 b/thread).
// W: async global_load_lds, 4-channel chunks (20KB), double-buffered.
// Thread map: u = tid>>4, bq = tid&15 -> wave = 4u x 16bq:
//   W ds_read_b128: 4 distinct addrs on 4 distinct bank-quads (conflict-free)
//   x ds reads: 16 addrs stride 2 dwords, 4-lane broadcast (conflict-free)
__global__ __launch_bounds__(256, 2) void s_pass(const float* __restrict__ x,
                                                 const float* __restrict__ W,
                                                 const float* __restrict__ cT,
                                                 float* __restrict__ sp,
                                                 float scale) {
    __shared__ float wbuf[2 * 5120];     // 2 x (4c * 10d * 16u * 8i) = 40 KB
    __shared__ float xs[16 * IU * 32];   // [cc][i][bl] 16 KB
    __shared__ float cl[NU * 16];
    const int tid = threadIdx.x;
    const int lane = tid & 63;
    const int wid = tid >> 6;
    const int ch = blockIdx.x % SNC;
    const int bt = blockIdx.x / SNC;
    const int b0 = bt * 32, c0 = ch * 16;

    const float* wsrc = W + (size_t)c0 * (NU * US * IU);   // 16 channels * 1280

    // issue async W chunk 0 (4 channels = 5120 floats); wave w covers 5 KB
#pragma unroll
    for (int k = 0; k < 5; k++)
        gl_lds16(wsrc + (wid * 5 + k) * 256 + lane * 4, &wbuf[(wid * 5 + k) * 256]);

    // x stage -> xs[cc][i][bl]
#pragma unroll
    for (int k = 0; k < 4; k++) {
        int j = tid + k * 256;
        int q = j & 3, i = (j >> 2) & 7, bl = j >> 5;
        float4 t = *(const float4*)(x + (size_t)(b0 + bl) * (IU * IC) + i * IC + c0 + q * 4);
        xs[((q * 4 + 0) * IU + i) * 32 + bl] = t.x;
        xs[((q * 4 + 1) * IU + i) * 32 + bl] = t.y;
        xs[((q * 4 + 2) * IU + i) * 32 + bl] = t.z;
        xs[((q * 4 + 3) * IU + i) * 32 + bl] = t.w;
    }
    if (tid < NU * 16) {
        int d = tid >> 4, cc = tid & 15;
        cl[d * 16 + cc] = cT ? cT[d * IC + c0 + cc] : 1.0f;
    }
    __syncthreads();   // drains async chunk 0 (vmcnt0 before barrier) + x/cl visible

    const int uq = tid >> 4;      // u index 0..15 (4 per wave)
    const int bq = tid & 15;      // batch pair 0..15
    float acc[NU][2];
#pragma unroll
    for (int d = 0; d < NU; d++) acc[d][0] = acc[d][1] = 0.0f;

    for (int cch = 0; cch < 4; cch++) {
        const int cur = cch & 1;
        if (cch < 3) {   // issue next chunk into the other buffer (async, no VGPR)
            const float* wnext = wsrc + (cch + 1) * 5120;
#pragma unroll
            for (int k = 0; k < 5; k++)
                gl_lds16(wnext + (wid * 5 + k) * 256 + lane * 4,
                         &wbuf[(1 - cur) * 5120 + (wid * 5 + k) * 256]);
        }
#pragma unroll
        for (int c4 = 0; c4 < 4; c4++) {
            const int cc = cch * 4 + c4;
            float xv0[IU], xv1[IU];
#pragma unroll
            for (int i = 0; i < IU; i++) {
                xv0[i] = xs[(cc * IU + i) * 32 + bq * 2 + 0];
                xv1[i] = xs[(cc * IU + i) * 32 + bq * 2 + 1];
            }
            const float* wb = &wbuf[cur * 5120 + (c4 * NU) * US * IU + uq * IU];
#pragma unroll
            for (int d = 0; d < NU; d++) {
                float4 w0 = *(const float4*)(wb + d * (US * IU));
                float4 w1 = *(const float4*)(wb + d * (US * IU) + 4);
                float cw = cl[d * 16 + cc];
                float d0 = w0.x*xv0[0] + w0.y*xv0[1] + w0.z*xv0[2] + w0.w*xv0[3]
                         + w1.x*xv0[4] + w1.y*xv0[5] + w1.z*xv0[6] + w1.w*xv0[7];
                float d1 = w0.x*xv1[0] + w0.y*xv1[1] + w0.z*xv1[2] + w0.w*xv1[3]
                         + w1.x*xv1[4] + w1.y*xv1[5] + w1.z*xv1[6] + w1.w*xv1[7];
                acc[d][0] += cw * d0;
                acc[d][1] += cw * d1;
            }
        }
        __syncthreads();   // buf[cur] consumed by all; next chunk drained by barrier's vmcnt
    }
#pragma unroll
    for (int bb = 0; bb < 2; bb++) {
        const int b = b0 + bq * 2 + bb;
#pragma unroll
        for (int d = 0; d < NU; d++)
            sp[(((size_t)ch * B + b) * NU + d) * US + uq] = acc[d][bb] * scale;
    }
}

// ---------------- squash ----------------
__global__ __launch_bounds__(192) void squash_k(const float* __restrict__ sp,
                                                float* __restrict__ vout, int nc) {
    __shared__ float smag[NU * US];
    const int b = blockIdx.x;
    const int tid = threadIdx.x;
    const int d = tid >> 4, uq = tid & 15;
    float s = 0.0f;
    if (d < NU) {
        for (int chp = 0; chp < nc; chp++)
            s += sp[(((size_t)chp * B + b) * NU + d) * US + uq];
        smag[d * US + uq] = s * s;
    }
    __syncthreads();
    if (d < NU) {
        float msq = 0.0f;
#pragma unroll
        for (int dd = 0; dd < NU; dd++) msq += smag[dd * US + uq];
        float f = msq / ((1.0f + msq) * sqrtf(msq));
        vout[((size_t)b * NU + d) * US + uq] = s * f;
    }
}

// ---------------- agree pass v4 ----------------
// agree[c,d] = sum_{b,u,i} W[c,d,u,i] * x[b,i,c] * v[b,d,u]
// grid 576 = 72 ct(16c) x 8 bt(32b, 2 b/thread). Thread owns (cc=tid&15, bq=tid>>4);
// x in regs (loaded once), W slice (80KB) + v (padded) in LDS.
// u_eff=(u+cc)&15 rotation cuts W read conflicts 16-way -> 4-way.
__global__ __launch_bounds__(256, 1) void agree_k(const float* __restrict__ x,
                                                  const float* __restrict__ W,
                                                  const float* __restrict__ v,
                                                  float* __restrict__ ap) {
    __shared__ float wl[16 * NU * US * IU];   // [cc][d][u][i] identity, 80 KB
    __shared__ float vl[32 * 170];            // [bl][d*17+u] padded, 21.3 KB
    __shared__ float xs[IU * 32 * 16];        // [i][bl][cc] 16 KB (reused as red)
    const int tid = threadIdx.x;
    const int ct = blockIdx.x % SNC;
    const int bt = blockIdx.x / SNC;
    const int c0 = ct * 16, b0 = bt * 32;

    // W slice: 5120 float4, coalesced, identity layout
    const float* wsrc = W + (size_t)c0 * (NU * US * IU);
#pragma unroll
    for (int k = 0; k < 20; k++) {
        int j = tid + k * 256;
        *(float4*)&wl[j * 4] = *(const float4*)(wsrc + (size_t)j * 4);
    }
    // v -> padded [bl][d*17+u]
#pragma unroll
    for (int k = 0; k < 20; k++) {
        int j = tid + k * 256;
        if (j < 32 * 160) {
            int bl = j / 160, q = j % 160, d = q >> 4, u = q & 15;
            vl[bl * 170 + d * 17 + u] = v[((size_t)(b0 + bl) * NU + d) * US + u];
        }
    }
    // x -> xs[i][bl][cc]
#pragma unroll
    for (int k = 0; k < 4; k++) {
        int j = tid + k * 256;
        int q = j & 3, i = (j >> 2) & 7, bl = j >> 5;
        float4 t = *(const float4*)(x + (size_t)(b0 + bl) * (IU * IC) + i * IC + c0 + q * 4);
        xs[(i * 32 + bl) * 16 + q * 4 + 0] = t.x;
        xs[(i * 32 + bl) * 16 + q * 4 + 1] = t.y;
        xs[(i * 32 + bl) * 16 + q * 4 + 2] = t.z;
        xs[(i * 32 + bl) * 16 + q * 4 + 3] = t.w;
    }
    __syncthreads();

    const int cc = tid & 15;
    const int bq = tid >> 4;
    // x for this thread's (cc, 2 b) into regs
    float xv0[IU], xv1[IU];
#pragma unroll
    for (int i = 0; i < IU; i++) {
        xv0[i] = xs[(i * 32 + bq * 2 + 0) * 16 + cc];
        xv1[i] = xs[(i * 32 + bq * 2 + 1) * 16 + cc];
    }
    __syncthreads();   // xs consumed by everyone; safe to reuse as reduction buffer
    float* red = xs;   // needs 256*10 = 2560 floats

    float acc[NU];
#pragma unroll
    for (int d = 0; d < NU; d++) acc[d] = 0.0f;

    const float* wrow = &wl[cc * (NU * US * IU)];
    const float* vr0 = &vl[(bq * 2 + 0) * 170];
    const float* vr1 = &vl[(bq * 2 + 1) * 170];
#pragma unroll
    for (int d = 0; d < NU; d++) {
        float a = 0.0f;
#pragma unroll
        for (int u = 0; u < US; u++) {
            const int ue = (u + cc) & 15;
            const float* wr = wrow + (d * US + ue) * IU;
            float4 w0 = *(const float4*)(wr);
            float4 w1 = *(const float4*)(wr + 4);
            float uh0 = w0.x*xv0[0] + w0.y*xv0[1] + w0.z*xv0[2] + w0.w*xv0[3]
                      + w1.x*xv0[4] + w1.y*xv0[5] + w1.z*xv0[6] + w1.w*xv0[7];
            float uh1 = w0.x*xv1[0] + w0.y*xv1[1] + w0.z*xv1[2] + w0.w*xv1[3]
                      + w1.x*xv1[4] + w1.y*xv1[5] + w1.z*xv1[6] + w1.w*xv1[7];
            a += uh0 * vr0[d * 17 + ue] + uh1 * vr1[d * 17 + ue];
        }
        acc[d] = a;
    }
#pragma unroll
    for (int d = 0; d < NU; d++) red[tid * NU + d] = acc[d];
    __syncthreads();
    if (tid < 160) {
        const int rc = tid & 15, rd = tid >> 4;
        float s = 0.0f;
#pragma unroll
        for (int g = 0; g < 16; g++) s += red[(g * 16 + rc) * NU + rd];
        ap[((size_t)bt * NU + rd) * IC + c0 + rc] = s;
    }
}

// ---------------- b update + softmax over channels ----------------
__global__ __launch_bounds__(384) void bsm_k(const float* __restrict__ ap,
                                             float* __restrict__ bij,
                                             float* __restrict__ cT,
                                             int first) {
    __shared__ float wred[8];
    __shared__ float bcast;
    const int d = blockIdx.x;
    const int tid = threadIdx.x;
    float bn[3];
    float lmax = -1e30f;
#pragma unroll
    for (int k = 0; k < 3; k++) {
        int c = tid + k * 384;
        float a = 0.0f;
#pragma unroll
        for (int g = 0; g < 8; g++) a += ap[((size_t)g * NU + d) * IC + c];
        a *= (1.0f / (float)B);
        float bo = first ? 0.0f : bij[d * IC + c];
        bn[k] = bo + a;
        bij[d * IC + c] = bn[k];
        lmax = fmaxf(lmax, bn[k]);
    }
    for (int off = 32; off > 0; off >>= 1) lmax = fmaxf(lmax, __shfl_down(lmax, off, 64));
    const int wid = tid >> 6, lane = tid & 63;
    if (lane == 0) wred[wid] = lmax;
    __syncthreads();
    if (tid == 0) {
        float m = wred[0];
        for (int w_ = 1; w_ < 6; w_++) m = fmaxf(m, wred[w_]);
        bcast = m;
    }
    __syncthreads();
    const float mx = bcast;
    float e[3];
    float lsum = 0.0f;
#pragma unroll
    for (int k = 0; k < 3; k++) { e[k] = expf(bn[k] - mx); lsum += e[k]; }
    for (int off = 32; off > 0; off >>= 1) lsum += __shfl_down(lsum, off, 64);
    if (lane == 0) wred[wid] = lsum;
    __syncthreads();
    if (tid == 0) {
        float s2 = 0.0f;
        for (int w_ = 0; w_ < 6; w_++) s2 += wred[w_];
        bcast = 1.0f / s2;
    }
    __syncthreads();
    const float inv = bcast;
#pragma unroll
    for (int k = 0; k < 3; k++) cT[d * IC + tid + k * 384] = e[k] * inv;
}

extern "C" void kernel_launch(void* const* d_in, const int* in_sizes, int n_in,
                              void* d_out, int out_size, void* d_ws, size_t ws_size,
                              hipStream_t stream) {
    const float* x = (const float*)d_in[0];   // [256, 8, 1152]
    const float* W = (const float*)d_in[1];   // [1, 1152, 10, 16, 8]
    float* out = (float*)d_out;               // [256, 10, 16] fp32

    // workspace (floats), ~12.4 MB total (known budget >= 15.85 MB from R3)
    float* sp  = (float*)d_ws;                       // 72*256*160 = 2,949,120
    float* v   = sp + (size_t)SNC * B * NU * US;     // 40,960
    float* bij = v + (size_t)B * NU * US;            // 11,520  [d][c]
    float* cT  = bij + (size_t)NU * IC;              // 11,520  [d][c]
    float* apg = cT + (size_t)NU * IC;               // 8*10*1152 = 92,160

    const float inv_ic = 1.0f / (float)IC;

    // iteration 1 (c uniform = 1/1152)
    s_pass<<<576, 256, 0, stream>>>(x, W, nullptr, sp, inv_ic);
    squash_k<<<B, 192, 0, stream>>>(sp, v, SNC);
    agree_k<<<576, 256, 0, stream>>>(x, W, v, apg);
    bsm_k<<<NU, 384, 0, stream>>>(apg, bij, cT, 1);
    // iteration 2
    s_pass<<<576, 256, 0, stream>>>(x, W, cT, sp, 1.0f);
    squash_k<<<B, 192, 0, stream>>>(sp, v, SNC);
    agree_k<<<576, 256, 0, stream>>>(x, W, v, apg);
    bsm_k<<<NU, 384, 0, stream>>>(apg, bij, cT, 0);
    // iteration 3 (agree not needed after final squash)
    s_pass<<<576, 256, 0, stream>>>(x, W, cT, sp, 1.0f);
    squash_k<<<B, 192, 0, stream>>>(sp, out, SNC);
}